// Round 9
// baseline (473.885 us; speedup 1.0000x reference)
//
#include <hip/hip_runtime.h>
#include <math.h>

#define RANK 33
#define D 32            // rank-1 (space dims)
#define N_ENT 50000
#define N_PAD 50176     // 98 * 512
#define N_REL 500
#define NQ 2000
#define M_PAD 2048      // lhsB rows allocated/zeroed
#define KP 64           // K padded 33 -> 64
#define NXCD 8
#define STRIPES_PER_XCD 13   // ceil(98/8) -> 104 virtual stripes, guard at 98
#define MBANDS 63            // ceil(2000/32)

typedef float  f32x4  __attribute__((ext_vector_type(4)));
typedef short  bf16x8 __attribute__((ext_vector_type(8)));

__device__ __forceinline__ float waveReduceSum(float v) {
    #pragma unroll
    for (int off = 32; off > 0; off >>= 1)
        v += __shfl_xor(v, off, 64);
    return v;
}

__device__ __forceinline__ ushort f2bf(float f) {  // RTN-even
    union { float f; unsigned u; } c; c.f = f;
    return (ushort)((c.u + 0x7fffu + ((c.u >> 16) & 1u)) >> 16);
}

// ---------------- K1: expmap0 -> emb_bf16[N_PAD][KP], row-major, coalesced writes.
__global__ void k_expmap(const float* __restrict__ ent, ushort* __restrict__ embB) {
    int wave = (blockIdx.x * blockDim.x + threadIdx.x) >> 6;
    int lane = threadIdx.x & 63;
    if (wave >= N_PAD) return;
    float val = 0.0f;
    if (wave < N_ENT) {
        const float* u = ent + (long)wave * RANK;
        float uv = (lane < RANK) ? u[lane] : 0.0f;
        float en = sqrtf(waveReduceSum(uv * uv));
        float scale = fminf(1.0f, 2.0f / fmaxf(en, 1e-12f));
        uv *= scale;
        float sp2 = waveReduceSum((lane >= 1 && lane < RANK) ? uv * uv : 0.0f);
        float u0 = __shfl(uv, 0, 64);
        float nomin = sqrtf(fmaxf(sp2 - u0 * u0, 1e-8f));
        float s = sinhf(nomin) / nomin;
        float sv = s * uv;
        float t2 = waveReduceSum((lane >= 1 && lane < RANK) ? sv * sv : 0.0f);
        val = (lane == 0) ? sqrtf(1.0f + t2) : ((lane < RANK) ? sv : 0.0f);
    }
    float v0 = __shfl(val, (lane & 31) * 2, 64);
    float v1 = __shfl(val, (lane & 31) * 2 + 1, 64);
    if (lane < 32) {
        ushort2 p; p.x = f2bf(v0); p.y = f2bf(v1);
        *(ushort2*)(embB + (size_t)wave * KP + lane * 2) = p;
    }
}

// ---------------- K2: per-query transform -> lhs_bf16[M_PAD][KP] (rows pre-scaled by -2).
__global__ void k_query(const float* __restrict__ ent,
                        const float* __restrict__ rot_raw,
                        const float* __restrict__ boosts,
                        const int* __restrict__ queries,
                        ushort* __restrict__ lhsB) {
    int wave = (blockIdx.x * blockDim.x + threadIdx.x) >> 6;
    int lane = threadIdx.x & 63;
    if (wave >= M_PAD) return;
    float outv = 0.0f;
    if (wave < NQ) {
        int h = queries[wave * 3 + 0];
        int r = queries[wave * 3 + 1];
        // expmap0(ent[h])
        const float* u = ent + (long)h * RANK;
        float uv = (lane < RANK) ? u[lane] : 0.0f;
        float en = sqrtf(waveReduceSum(uv * uv));
        float scale = fminf(1.0f, 2.0f / fmaxf(en, 1e-12f));
        uv *= scale;
        float sp2 = waveReduceSum((lane >= 1 && lane < RANK) ? uv * uv : 0.0f);
        float u0 = __shfl(uv, 0, 64);
        float nomin = sqrtf(fmaxf(sp2 - u0 * u0, 1e-8f));
        float s = sinhf(nomin) / nomin;
        float sv = s * uv;
        float t2 = waveReduceSum((lane >= 1 && lane < RANK) ? sv * sv : 0.0f);
        float lhs_t = sqrtf(1.0f + t2);
        // lane i < 32 owns space dim i
        float x = __shfl(sv, (lane + 1) & 63, 64);
        if (lane >= D) x = 0.0f;
        // x^T (H_0..H_31) = H_31(..(H_0 x))  (each H_k symmetric)
        const float* rr = rot_raw + (long)r * D * D;
        for (int k = 0; k < D; ++k) {
            float g = 0.0f;
            if (lane < D) {
                float w = rr[k * D + lane];
                g = 0.5f * w * (1.0f + erff(w * 0.70710678118654752f)); // exact gelu
            }
            float dvx = waveReduceSum(g * x);
            float n   = waveReduceSum(g * g);
            x -= (2.0f * dvx / n) * g;
        }
        // Lorentz boost
        float b = 0.0f;
        if (lane < D) b = tanhf(boosts[(long)r * D + lane]) * (1.0f / 33.0f);
        float b2   = waveReduceSum(b * b);
        float bdot = waveReduceSum(b * x);
        float zeta = 1.0f / (sqrtf(1.0f - b2) + 1e-8f);
        float x0 = zeta * lhs_t - zeta * bdot;
        float xr = -zeta * lhs_t * b + x + (zeta - 1.0f) / (b2 + 1e-9f) * b * bdot;
        // row = -2 * lhs_neg = [2*x0, -2*xr...]
        float xr_sh = __shfl(xr, (lane + 63) & 63, 64);
        outv = (lane == 0) ? 2.0f * x0 : ((lane < RANK) ? -2.0f * xr_sh : 0.0f);
    }
    float v0 = __shfl(outv, (lane & 31) * 2, 64);
    float v1 = __shfl(outv, (lane & 31) * 2 + 1, 64);
    if (lane < 32) {
        ushort2 p; p.x = f2bf(v0); p.y = f2bf(v1);
        *(ushort2*)(lhsB + (size_t)wave * KP + lane * 2) = p;
    }
}

// ---------------- K3: INSTRUMENTATION ROUND — identical to R8 but body runs
// `reps` times (idempotent: same addresses, same values). reps=2 makes this the
// top dispatch so rocprof reports its counters; K3_solo = T9 - T8.
__global__ __launch_bounds__(256, 4)
void k_scores(const ushort* __restrict__ lhsB,
              const ushort* __restrict__ embB,
              float* __restrict__ out, int reps) {
    int bid = blockIdx.x;
    int xcd = bid % NXCD;
    int idx = bid / NXCD;
    int stripe = xcd * STRIPES_PER_XCD + (idx % STRIPES_PER_XCD);
    int band   = idx / STRIPES_PER_XCD;
    if (stripe >= 98) return;
    int n0 = stripe * 512;
    int m0 = band * 32;

    int wid  = threadIdx.x >> 6;
    int lane = threadIdx.x & 63;
    int wm = wid & 1;        // m-half (16 rows)
    int wn = wid >> 1;       // n-quarter (256 cols = 16 tiles)
    int lr = lane & 15, rg = lane >> 4;

    const ushort* lrow = lhsB + (size_t)(m0 + wm * 16 + lr) * KP + rg * 8;
    bf16x8 l0 = *(const bf16x8*)(lrow);
    bf16x8 l1 = *(const bf16x8*)(lrow + 32);

    for (int rep = 0; rep < reps; ++rep) {
        f32x4 acc[16];
        #pragma unroll
        for (int nt = 0; nt < 16; ++nt) acc[nt] = f32x4{2.f, 2.f, 2.f, 2.f};

        const ushort* ebase = embB + (size_t)(n0 + wn * 256 + lr) * KP + rg * 8;
        #pragma unroll
        for (int nt = 0; nt < 16; ++nt) {
            const ushort* erow = ebase + (size_t)nt * 16 * KP;
            bf16x8 e0 = *(const bf16x8*)(erow);
            bf16x8 e1 = *(const bf16x8*)(erow + 32);
            acc[nt] = __builtin_amdgcn_mfma_f32_16x16x32_bf16(e0, l0, acc[nt], 0, 0, 0);
            acc[nt] = __builtin_amdgcn_mfma_f32_16x16x32_bf16(e1, l1, acc[nt], 0, 0, 0);
        }

        int m = m0 + wm * 16 + lr;
        if (m < NQ) {
            float* orow = out + (size_t)m * N_ENT;
            #pragma unroll
            for (int nt = 0; nt < 16; ++nt) {
                int nq = n0 + wn * 256 + nt * 16 + rg * 4;
                if (nq < N_ENT)
                    __builtin_nontemporal_store(acc[nt], (f32x4*)(orow + nq));
            }
        }
    }
}

// ---------------- K4a: per-relation norms (raw rot Frobenius + boost L2).
__global__ void k_norms(const float* __restrict__ rot_raw,
                        const float* __restrict__ boosts,
                        float* __restrict__ rotF, float* __restrict__ boostN) {
    int wave = (blockIdx.x * blockDim.x + threadIdx.x) >> 6;
    int lane = threadIdx.x & 63;
    if (wave >= N_REL) return;
    const float* rr = rot_raw + (long)wave * (D * D);
    float s = 0.0f;
    #pragma unroll
    for (int i = 0; i < (D * D) / 64; ++i) {
        float w = rr[i * 64 + lane];
        s += w * w;
    }
    s = waveReduceSum(s);
    float sb = 0.0f;
    if (lane < D) { float w = boosts[(long)wave * D + lane]; sb = w * w; }
    sb = waveReduceSum(sb);
    if (lane == 0) { rotF[wave] = sqrtf(s); boostN[wave] = sqrtf(sb); }
}

// ---------------- K4b: reg[i,j] = rotF[j] + boostN[i]
__global__ void k_reg(const float* __restrict__ rotF, const float* __restrict__ boostN,
                      float* __restrict__ out) {
    int idx = blockIdx.x * blockDim.x + threadIdx.x;
    if (idx >= N_REL * N_REL) return;
    int i = idx / N_REL;
    int j = idx - i * N_REL;
    out[idx] = rotF[j] + boostN[i];
}

extern "C" void kernel_launch(void* const* d_in, const int* in_sizes, int n_in,
                              void* d_out, int out_size, void* d_ws, size_t ws_size,
                              hipStream_t stream) {
    const float* ent     = (const float*)d_in[0];   // 50000 x 33
    const float* rot     = (const float*)d_in[1];   // 500 x 32 x 32
    const float* boosts  = (const float*)d_in[2];   // 500 x 32
    const int*   queries = (const int*)d_in[3];     // 2000 x 3 (h, r, t)
    float* out = (float*)d_out;                     // scores (2000x50000) ++ reg (500x500)

    ushort* embB = (ushort*)d_ws;                        // N_PAD * 64 bf16 = 6.4 MB
    ushort* lhsB = embB + (size_t)N_PAD * KP;            // M_PAD * 64 bf16 = 256 KB
    float*  rotF   = (float*)(lhsB + (size_t)M_PAD * KP);
    float*  boostN = rotF + N_REL;

    hipLaunchKernelGGL(k_expmap, dim3(N_PAD / 4), dim3(256), 0, stream, ent, embB);
    hipLaunchKernelGGL(k_query, dim3(M_PAD / 4), dim3(256), 0, stream,
                       ent, rot, boosts, queries, lhsB);
    // INSTRUMENTATION: reps=2 (idempotent double-run to surface K3 in rocprof top-5)
    hipLaunchKernelGGL(k_scores, dim3(NXCD * STRIPES_PER_XCD * MBANDS), dim3(256), 0, stream,
                       lhsB, embB, out, 2);
    hipLaunchKernelGGL(k_norms, dim3((N_REL + 3) / 4), dim3(256), 0, stream,
                       rot, boosts, rotF, boostN);
    hipLaunchKernelGGL(k_reg, dim3((N_REL * N_REL + 255) / 256), dim3(256), 0, stream,
                       rotF, boostN, out + (size_t)NQ * N_ENT);
}

// Round 10
// 136.374 us; speedup vs baseline: 3.4749x; 3.4749x over previous
//
#include <hip/hip_runtime.h>
#include <math.h>

#define RANK 33
#define D 32            // rank-1 (space dims)
#define N_ENT 50000
#define N_REL 500
#define NQ 2000
#define W_PAD 50176     // embT row stride (98 * 512)
#define NQ_PAD 2048     // lhsT row stride
#define MT 100          // m per y-block in k_scores (grid y = 20)

typedef float f2v __attribute__((ext_vector_type(2)));

__device__ __forceinline__ float waveReduceSum(float v) {
    #pragma unroll
    for (int off = 32; off > 0; off >>= 1)
        v += __shfl_xor(v, off, 64);
    return v;
}

// ---------------- K1: expmap0, THREAD-per-entity -> embT[33][W_PAD] (dim-major).
// Each thread owns one entity; every dim-k write is a coalesced 256 B wave instr.
__global__ void k_expmap(const float* __restrict__ ent, float* __restrict__ embT) {
    int n = blockIdx.x * blockDim.x + threadIdx.x;
    if (n >= N_ENT) return;
    const float* u = ent + (size_t)n * RANK;
    float v[RANK];
    float en2 = 0.f;
    #pragma unroll
    for (int k = 0; k < RANK; ++k) { v[k] = u[k]; en2 += v[k] * v[k]; }
    float scale = fminf(1.0f, 2.0f / fmaxf(sqrtf(en2), 1e-12f));
    #pragma unroll
    for (int k = 0; k < RANK; ++k) v[k] *= scale;
    float sp2 = 0.f;
    #pragma unroll
    for (int k = 1; k < RANK; ++k) sp2 += v[k] * v[k];
    float nomin = sqrtf(fmaxf(sp2 - v[0] * v[0], 1e-8f));
    float s = sinhf(nomin) / nomin;
    float t2 = 0.f;
    #pragma unroll
    for (int k = 1; k < RANK; ++k) { v[k] *= s; t2 += v[k] * v[k]; }
    embT[n] = sqrtf(1.0f + t2);                       // time row (k = 0)
    #pragma unroll
    for (int k = 1; k < RANK; ++k)
        embT[(size_t)k * W_PAD + n] = v[k];           // coalesced per k
}

// ---------------- K2: per-query transform -> lhsT[33][NQ_PAD] (lhs_neg, dim-major).
// One wave per query (reductions via shfl); 33 scattered dwords/query is negligible.
__global__ void k_query(const float* __restrict__ ent,
                        const float* __restrict__ rot_raw,
                        const float* __restrict__ boosts,
                        const int* __restrict__ queries,
                        float* __restrict__ lhsT) {
    int wave = (blockIdx.x * blockDim.x + threadIdx.x) >> 6;
    int lane = threadIdx.x & 63;
    if (wave >= NQ) return;
    int h = queries[wave * 3 + 0];
    int r = queries[wave * 3 + 1];
    // expmap0(ent[h])
    const float* u = ent + (long)h * RANK;
    float uv = (lane < RANK) ? u[lane] : 0.0f;
    float en = sqrtf(waveReduceSum(uv * uv));
    float scale = fminf(1.0f, 2.0f / fmaxf(en, 1e-12f));
    uv *= scale;
    float sp2 = waveReduceSum((lane >= 1 && lane < RANK) ? uv * uv : 0.0f);
    float u0 = __shfl(uv, 0, 64);
    float nomin = sqrtf(fmaxf(sp2 - u0 * u0, 1e-8f));
    float s = sinhf(nomin) / nomin;
    float sv = s * uv;
    float t2 = waveReduceSum((lane >= 1 && lane < RANK) ? sv * sv : 0.0f);
    float lhs_t = sqrtf(1.0f + t2);
    // lane i < 32 owns space dim i
    float x = __shfl(sv, (lane + 1) & 63, 64);
    if (lane >= D) x = 0.0f;
    // x^T (H_0..H_31) = H_31(..(H_0 x))  (each H_k symmetric)
    const float* rr = rot_raw + (long)r * D * D;
    for (int k = 0; k < D; ++k) {
        float g = 0.0f;
        if (lane < D) {
            float w = rr[k * D + lane];
            g = 0.5f * w * (1.0f + erff(w * 0.70710678118654752f)); // exact gelu
        }
        float dvx = waveReduceSum(g * x);
        float n   = waveReduceSum(g * g);
        x -= (2.0f * dvx / n) * g;
    }
    // Lorentz boost
    float b = 0.0f;
    if (lane < D) b = tanhf(boosts[(long)r * D + lane]) * (1.0f / 33.0f);
    float b2   = waveReduceSum(b * b);
    float bdot = waveReduceSum(b * x);
    float zeta = 1.0f / (sqrtf(1.0f - b2) + 1e-8f);
    float x0 = zeta * lhs_t - zeta * bdot;
    float xr = -zeta * lhs_t * b + x + (zeta - 1.0f) / (b2 + 1e-9f) * b * bdot;
    if (lane < D) lhsT[(size_t)(1 + lane) * NQ_PAD + wave] = xr;
    if (lane == 0) lhsT[wave] = -x0;     // negated time component
}

// ---------------- K3: scores = 2 - 2 * lhs_neg @ emb^T  (R2-proven fp32 structure).
// Thread owns 2 adjacent n; 4 m per inner tile (one uniform float4 l-load per k
// feeds 8 FMAs). Wave store = 512 B contiguous per m row. MT=100 -> 1960 blocks.
__global__ void k_scores(const float* __restrict__ lhsT,
                         const float* __restrict__ embT,
                         float* __restrict__ out) {
    int t = threadIdx.x;
    int n = blockIdx.x * 512 + t * 2;
    if (n >= N_ENT) return;
    int m0 = blockIdx.y * MT;
    f2v e[RANK];
    #pragma unroll
    for (int k = 0; k < RANK; ++k)
        e[k] = *(const f2v*)(embT + (size_t)k * W_PAD + n);
    for (int mt = m0; mt < m0 + MT; mt += 4) {
        float a0x = 0.f, a0y = 0.f, a1x = 0.f, a1y = 0.f;
        float a2x = 0.f, a2y = 0.f, a3x = 0.f, a3y = 0.f;
        #pragma unroll
        for (int k = 0; k < RANK; ++k) {
            float4 l = *(const float4*)(lhsT + k * NQ_PAD + mt);
            float ex = e[k].x, ey = e[k].y;
            a0x = fmaf(l.x, ex, a0x); a0y = fmaf(l.x, ey, a0y);
            a1x = fmaf(l.y, ex, a1x); a1y = fmaf(l.y, ey, a1y);
            a2x = fmaf(l.z, ex, a2x); a2y = fmaf(l.z, ey, a2y);
            a3x = fmaf(l.w, ex, a3x); a3y = fmaf(l.w, ey, a3y);
        }
        f2v s0 = {2.f - 2.f * a0x, 2.f - 2.f * a0y};
        f2v s1 = {2.f - 2.f * a1x, 2.f - 2.f * a1y};
        f2v s2 = {2.f - 2.f * a2x, 2.f - 2.f * a2y};
        f2v s3 = {2.f - 2.f * a3x, 2.f - 2.f * a3y};
        __builtin_nontemporal_store(s0, (f2v*)(out + (size_t)(mt + 0) * N_ENT + n));
        __builtin_nontemporal_store(s1, (f2v*)(out + (size_t)(mt + 1) * N_ENT + n));
        __builtin_nontemporal_store(s2, (f2v*)(out + (size_t)(mt + 2) * N_ENT + n));
        __builtin_nontemporal_store(s3, (f2v*)(out + (size_t)(mt + 3) * N_ENT + n));
    }
}

// ---------------- K4a: per-relation norms (raw rot Frobenius + boost L2).
__global__ void k_norms(const float* __restrict__ rot_raw,
                        const float* __restrict__ boosts,
                        float* __restrict__ rotF, float* __restrict__ boostN) {
    int wave = (blockIdx.x * blockDim.x + threadIdx.x) >> 6;
    int lane = threadIdx.x & 63;
    if (wave >= N_REL) return;
    const float* rr = rot_raw + (long)wave * (D * D);
    float s = 0.0f;
    #pragma unroll
    for (int i = 0; i < (D * D) / 64; ++i) {
        float w = rr[i * 64 + lane];
        s += w * w;
    }
    s = waveReduceSum(s);
    float sb = 0.0f;
    if (lane < D) { float w = boosts[(long)wave * D + lane]; sb = w * w; }
    sb = waveReduceSum(sb);
    if (lane == 0) { rotF[wave] = sqrtf(s); boostN[wave] = sqrtf(sb); }
}

// ---------------- K4b: reg[i,j] = rotF[j] + boostN[i]
__global__ void k_reg(const float* __restrict__ rotF, const float* __restrict__ boostN,
                      float* __restrict__ out) {
    int idx = blockIdx.x * blockDim.x + threadIdx.x;
    if (idx >= N_REL * N_REL) return;
    int i = idx / N_REL;
    int j = idx - i * N_REL;
    out[idx] = rotF[j] + boostN[i];
}

extern "C" void kernel_launch(void* const* d_in, const int* in_sizes, int n_in,
                              void* d_out, int out_size, void* d_ws, size_t ws_size,
                              hipStream_t stream) {
    const float* ent     = (const float*)d_in[0];   // 50000 x 33
    const float* rot     = (const float*)d_in[1];   // 500 x 32 x 32
    const float* boosts  = (const float*)d_in[2];   // 500 x 32
    const int*   queries = (const int*)d_in[3];     // 2000 x 3 (h, r, t)
    float* out = (float*)d_out;                     // scores (2000x50000) ++ reg (500x500)

    float* ws     = (float*)d_ws;
    float* embT   = ws;                               // 33 * 50176 = 1,655,808 floats
    float* lhsT   = ws + (size_t)RANK * W_PAD;        // 33 * 2048  =    67,584 floats
    float* rotF   = lhsT + (size_t)RANK * NQ_PAD;     //       500 floats
    float* boostN = rotF + N_REL;                     //       500 floats

    hipLaunchKernelGGL(k_expmap, dim3((N_ENT + 255) / 256), dim3(256), 0, stream, ent, embT);
    hipLaunchKernelGGL(k_query, dim3(NQ / 4), dim3(256), 0, stream,
                       ent, rot, boosts, queries, lhsT);
    hipLaunchKernelGGL(k_scores, dim3(98, NQ / MT), dim3(256), 0, stream,
                       lhsT, embT, out);
    hipLaunchKernelGGL(k_norms, dim3((N_REL + 3) / 4), dim3(256), 0, stream,
                       rot, boosts, rotF, boostN);
    hipLaunchKernelGGL(k_reg, dim3((N_REL * N_REL + 255) / 256), dim3(256), 0, stream,
                       rotF, boostN, out + (size_t)NQ * N_ENT);
}

// Round 11
// 132.867 us; speedup vs baseline: 3.5666x; 1.0264x over previous
//
#include <hip/hip_runtime.h>
#include <math.h>

#define RANK 33
#define D 32            // rank-1 (space dims)
#define N_ENT 50000
#define N_REL 500
#define NQ 2000
#define W_PAD 50176     // embT row stride (98 * 512)
#define NQ_PAD 2048     // lhsT row stride
#define MT 200          // m per y-block in k_scores (grid y = 10)

#define EXP_BLK 196     // ceil(50000/256) thread-per-entity blocks
#define QRY_BLK 500     // 2000 queries / 4 waves
#define NRM_BLK 125     // 500 relations / 4 waves

typedef float f2v __attribute__((ext_vector_type(2)));

__device__ __forceinline__ float waveReduceSum(float v) {
    #pragma unroll
    for (int off = 32; off > 0; off >>= 1)
        v += __shfl_xor(v, off, 64);
    return v;
}

// ---------------- K1 (fused prep): expmap-all | query-transform | rel-norms.
__global__ void k_prep(const float* __restrict__ ent,
                       const float* __restrict__ rot_raw,
                       const float* __restrict__ boosts,
                       const int* __restrict__ queries,
                       float* __restrict__ embT, float* __restrict__ lhsT,
                       float* __restrict__ rotF, float* __restrict__ boostN) {
    int bid = blockIdx.x;
    if (bid < EXP_BLK) {
        // ---- expmap0, thread-per-entity -> embT[33][W_PAD] (dim-major, coalesced)
        int n = bid * blockDim.x + threadIdx.x;
        if (n >= N_ENT) return;
        const float* u = ent + (size_t)n * RANK;
        float v[RANK];
        float en2 = 0.f;
        #pragma unroll
        for (int k = 0; k < RANK; ++k) { v[k] = u[k]; en2 += v[k] * v[k]; }
        float scale = fminf(1.0f, 2.0f / fmaxf(sqrtf(en2), 1e-12f));
        #pragma unroll
        for (int k = 0; k < RANK; ++k) v[k] *= scale;
        float sp2 = 0.f;
        #pragma unroll
        for (int k = 1; k < RANK; ++k) sp2 += v[k] * v[k];
        float nomin = sqrtf(fmaxf(sp2 - v[0] * v[0], 1e-8f));
        float s = sinhf(nomin) / nomin;
        float t2 = 0.f;
        #pragma unroll
        for (int k = 1; k < RANK; ++k) { v[k] *= s; t2 += v[k] * v[k]; }
        embT[n] = sqrtf(1.0f + t2);
        #pragma unroll
        for (int k = 1; k < RANK; ++k)
            embT[(size_t)k * W_PAD + n] = v[k];
    } else if (bid < EXP_BLK + QRY_BLK) {
        // ---- per-query transform, wave-per-query -> lhsT[33][NQ_PAD] (lhs_neg)
        int wave = (bid - EXP_BLK) * 4 + (threadIdx.x >> 6);
        int lane = threadIdx.x & 63;
        if (wave >= NQ) return;
        int h = queries[wave * 3 + 0];
        int r = queries[wave * 3 + 1];
        const float* u = ent + (long)h * RANK;
        float uv = (lane < RANK) ? u[lane] : 0.0f;
        float en = sqrtf(waveReduceSum(uv * uv));
        float scale = fminf(1.0f, 2.0f / fmaxf(en, 1e-12f));
        uv *= scale;
        float sp2 = waveReduceSum((lane >= 1 && lane < RANK) ? uv * uv : 0.0f);
        float u0 = __shfl(uv, 0, 64);
        float nomin = sqrtf(fmaxf(sp2 - u0 * u0, 1e-8f));
        float s = sinhf(nomin) / nomin;
        float sv = s * uv;
        float t2 = waveReduceSum((lane >= 1 && lane < RANK) ? sv * sv : 0.0f);
        float lhs_t = sqrtf(1.0f + t2);
        float x = __shfl(sv, (lane + 1) & 63, 64);
        if (lane >= D) x = 0.0f;
        // x^T (H_0..H_31) = H_31(..(H_0 x))  (each H_k symmetric)
        const float* rr = rot_raw + (long)r * D * D;
        for (int k = 0; k < D; ++k) {
            float g = 0.0f;
            if (lane < D) {
                float w = rr[k * D + lane];
                g = 0.5f * w * (1.0f + erff(w * 0.70710678118654752f)); // exact gelu
            }
            float dvx = waveReduceSum(g * x);
            float n   = waveReduceSum(g * g);
            x -= (2.0f * dvx / n) * g;
        }
        float b = 0.0f;
        if (lane < D) b = tanhf(boosts[(long)r * D + lane]) * (1.0f / 33.0f);
        float b2   = waveReduceSum(b * b);
        float bdot = waveReduceSum(b * x);
        float zeta = 1.0f / (sqrtf(1.0f - b2) + 1e-8f);
        float x0 = zeta * lhs_t - zeta * bdot;
        float xr = -zeta * lhs_t * b + x + (zeta - 1.0f) / (b2 + 1e-9f) * b * bdot;
        if (lane < D) lhsT[(size_t)(1 + lane) * NQ_PAD + wave] = xr;
        if (lane == 0) lhsT[wave] = -x0;
    } else {
        // ---- per-relation norms (raw rot Frobenius + boost L2)
        int wave = (bid - EXP_BLK - QRY_BLK) * 4 + (threadIdx.x >> 6);
        int lane = threadIdx.x & 63;
        if (wave >= N_REL) return;
        const float* rr = rot_raw + (long)wave * (D * D);
        float s = 0.0f;
        #pragma unroll
        for (int i = 0; i < (D * D) / 64; ++i) {
            float w = rr[i * 64 + lane];
            s += w * w;
        }
        s = waveReduceSum(s);
        float sb = 0.0f;
        if (lane < D) { float w = boosts[(long)wave * D + lane]; sb = w * w; }
        sb = waveReduceSum(sb);
        if (lane == 0) { rotF[wave] = sqrtf(s); boostN[wave] = sqrtf(sb); }
    }
}

// ---------------- K2: reg[i,j] = rotF[j] + boostN[i]
__global__ void k_reg(const float* __restrict__ rotF, const float* __restrict__ boostN,
                      float* __restrict__ out) {
    int idx = blockIdx.x * blockDim.x + threadIdx.x;
    if (idx >= N_REL * N_REL) return;
    int i = idx / N_REL;
    int j = idx - i * N_REL;
    out[idx] = rotF[j] + boostN[i];
}

// ---------------- K3: scores = 2 - 2 * lhs_neg @ emb^T  (fp32, traffic-minimal).
// Thread owns 2 adjacent n; e[33] held in regs for the whole block (one embT
// read per block). MT=200 -> 10 m-bands => embT HBM re-fetch ~66 MB total.
__global__ void k_scores(const float* __restrict__ lhsT,
                         const float* __restrict__ embT,
                         float* __restrict__ out) {
    int t = threadIdx.x;
    int n = blockIdx.x * 512 + t * 2;
    if (n >= N_ENT) return;
    int m0 = blockIdx.y * MT;
    f2v e[RANK];
    #pragma unroll
    for (int k = 0; k < RANK; ++k)
        e[k] = *(const f2v*)(embT + (size_t)k * W_PAD + n);
    for (int mt = m0; mt < m0 + MT; mt += 4) {
        float a0x = 0.f, a0y = 0.f, a1x = 0.f, a1y = 0.f;
        float a2x = 0.f, a2y = 0.f, a3x = 0.f, a3y = 0.f;
        #pragma unroll
        for (int k = 0; k < RANK; ++k) {
            float4 l = *(const float4*)(lhsT + k * NQ_PAD + mt);
            float ex = e[k].x, ey = e[k].y;
            a0x = fmaf(l.x, ex, a0x); a0y = fmaf(l.x, ey, a0y);
            a1x = fmaf(l.y, ex, a1x); a1y = fmaf(l.y, ey, a1y);
            a2x = fmaf(l.z, ex, a2x); a2y = fmaf(l.z, ey, a2y);
            a3x = fmaf(l.w, ex, a3x); a3y = fmaf(l.w, ey, a3y);
        }
        f2v s0 = {2.f - 2.f * a0x, 2.f - 2.f * a0y};
        f2v s1 = {2.f - 2.f * a1x, 2.f - 2.f * a1y};
        f2v s2 = {2.f - 2.f * a2x, 2.f - 2.f * a2y};
        f2v s3 = {2.f - 2.f * a3x, 2.f - 2.f * a3y};
        __builtin_nontemporal_store(s0, (f2v*)(out + (size_t)(mt + 0) * N_ENT + n));
        __builtin_nontemporal_store(s1, (f2v*)(out + (size_t)(mt + 1) * N_ENT + n));
        __builtin_nontemporal_store(s2, (f2v*)(out + (size_t)(mt + 2) * N_ENT + n));
        __builtin_nontemporal_store(s3, (f2v*)(out + (size_t)(mt + 3) * N_ENT + n));
    }
}

extern "C" void kernel_launch(void* const* d_in, const int* in_sizes, int n_in,
                              void* d_out, int out_size, void* d_ws, size_t ws_size,
                              hipStream_t stream) {
    const float* ent     = (const float*)d_in[0];   // 50000 x 33
    const float* rot     = (const float*)d_in[1];   // 500 x 32 x 32
    const float* boosts  = (const float*)d_in[2];   // 500 x 32
    const int*   queries = (const int*)d_in[3];     // 2000 x 3 (h, r, t)
    float* out = (float*)d_out;                     // scores (2000x50000) ++ reg (500x500)

    float* ws     = (float*)d_ws;
    float* embT   = ws;                               // 33 * 50176 floats
    float* lhsT   = ws + (size_t)RANK * W_PAD;        // 33 * 2048 floats
    float* rotF   = lhsT + (size_t)RANK * NQ_PAD;     // 500
    float* boostN = rotF + N_REL;                     // 500

    hipLaunchKernelGGL(k_prep, dim3(EXP_BLK + QRY_BLK + NRM_BLK), dim3(256), 0, stream,
                       ent, rot, boosts, queries, embT, lhsT, rotF, boostN);
    hipLaunchKernelGGL(k_reg, dim3((N_REL * N_REL + 255) / 256), dim3(256), 0, stream,
                       rotF, boostN, out + (size_t)NQ * N_ENT);
    hipLaunchKernelGGL(k_scores, dim3(98, NQ / MT), dim3(256), 0, stream,
                       lhsT, embT, out);
}